// Round 14
// baseline (425.194 us; speedup 1.0000x reference)
//
#include <hip/hip_runtime.h>
#include <hip/hip_bf16.h>
#include <math.h>

typedef unsigned short u16;
typedef __bf16 bf16x8 __attribute__((ext_vector_type(8)));
typedef float f32x4 __attribute__((ext_vector_type(4)));
typedef unsigned short u16x8 __attribute__((ext_vector_type(8)));
typedef unsigned short u16x4 __attribute__((ext_vector_type(4)));
typedef unsigned short u16x2 __attribute__((ext_vector_type(2)));

#define DEV static __device__ __forceinline__

DEV float b2f(u16 v) { unsigned u = ((unsigned)v) << 16; return __builtin_bit_cast(float, u); }
DEV u16 f2bf(float f) {
  unsigned u = __builtin_bit_cast(unsigned, f);
  u += 0x7fffu + ((u >> 16) & 1u);
  return (u16)(u >> 16);
}

DEV void async16(const void* g, void* l) {
  __builtin_amdgcn_global_load_lds(
      (const __attribute__((address_space(1))) void*)g,
      (__attribute__((address_space(3))) void*)l, 16, 0, 0);
}

// ---------------------------------------------------------------------------
// One-shot f32 -> bf16 conversion of x + all 4 weight matrices.
// ---------------------------------------------------------------------------
__global__ __launch_bounds__(256) void cvt_all_kernel(
    const float* __restrict__ x,  const float* __restrict__ wq,
    const float* __restrict__ wp, const float* __restrict__ w1,
    const float* __restrict__ w2,
    u16* __restrict__ dx, u16* __restrict__ dq, u16* __restrict__ dp,
    u16* __restrict__ d1, u16* __restrict__ d2)
{
  const int i = blockIdx.x * 256 + threadIdx.x;
  const float* s; u16* d; int off;
  if (i < 4194304)      { s = x;  d = dx; off = i; }
  else if (i < 4390912) { s = wq; d = dq; off = i - 4194304; }
  else if (i < 4456448) { s = wp; d = dp; off = i - 4390912; }
  else if (i < 4718592) { s = w1; d = d1; off = i - 4456448; }
  else if (i < 4980736) { s = w2; d = d2; off = i - 4718592; }
  else return;
  float4 v = ((const float4*)s)[off];
  u16x4 o;
  o[0] = f2bf(v.x); o[1] = f2bf(v.y); o[2] = f2bf(v.z); o[3] = f2bf(v.w);
  ((u16x4*)d)[off] = o;
}

// ---------------------------------------------------------------------------
// CPB stage 1 + stage 2
// ---------------------------------------------------------------------------
__global__ __launch_bounds__(64) void cpb1_kernel(
    const float* __restrict__ w1, const float* __restrict__ b1,
    const float* __restrict__ w2, float* __restrict__ tbl)
{
  const int r = blockIdx.x, h = blockIdx.y;
  const int lane = threadIdx.x;
  float rv = (float)(r - 63) * (8.0f / 63.0f);
  float sgn = (rv > 0.f) ? 1.f : ((rv < 0.f) ? -1.f : 0.f);
  float t = sgn * log2f(fabsf(rv) + 1.f) * (1.f / 3.f);
  float part = 0.f;
  for (int k = lane; k < 512; k += 64) {
    float hid = fmaxf(t * w1[k] + b1[k], 0.f);
    part += hid * w2[h * 512 + k];
  }
  #pragma unroll
  for (int o = 32; o > 0; o >>= 1) part += __shfl_down(part, o);
  if (lane == 0) tbl[r * 16 + h] = part;
}

__global__ __launch_bounds__(256) void cpb2_kernel(
    const float* __restrict__ tbl, float* __restrict__ btbl)
{
  const int h = blockIdx.x;
  for (int idx = threadIdx.x; idx < 4096; idx += 256) {
    int i = idx >> 6, j = idx & 63;
    float v = tbl[(i - j + 63) * 16 + h];
    btbl[h * 4096 + idx] = 16.f / (1.f + __expf(-v));
  }
}

// ---------------------------------------------------------------------------
// qkv GEMM — r11 m97-structure + minimal 2-phase double-buffer (BK=32):
// stage(next) -> ds_read(cur)+MFMA -> one __syncthreads per K-tile.
// LDS 32 KB -> 5 blocks/CU; launch_bounds(256,4).
// Race-safe: stage targets the buffer last read BEFORE the prior barrier.
// ---------------------------------------------------------------------------
__global__ __launch_bounds__(256, 4) void gemm_qkv(
    const u16* __restrict__ A, const u16* __restrict__ W,
    const float* __restrict__ bias1, const float* __restrict__ bias2,
    u16* __restrict__ out, int nby, int N, int K)
{
  __shared__ __attribute__((aligned(16))) u16 lA[2][4096];   // [128][32] swz
  __shared__ __attribute__((aligned(16))) u16 lB[2][4096];
  const int tid = threadIdx.x;
  const int lane = tid & 63;
  const int wv = tid >> 6;
  const int q8 = (int)gridDim.x >> 3;
  const int swb = (blockIdx.x & 7) * q8 + (blockIdx.x >> 3);
  const int m0 = (swb / nby) * 128;
  const int n0 = (swb % nby) * 128;
  const int wm = (wv >> 1) * 64;
  const int wn = (wv & 1) * 64;
  const int fr = lane & 15;
  const int hi = lane >> 4;
  const int sr = tid >> 2;       // 0..63
  const int sp = tid & 3;
  f32x4 acc[4][4] = {};

  auto stage = [&](int b, int k0) {
    #pragma unroll
    for (int i = 0; i < 2; ++i) {
      const int r = i * 64 + sr;
      const int kk = k0 + ((sp ^ ((r >> 1) & 3)) << 3);
      const int mg = m0 + r;
      const int bb = mg >> 12;
      const int p = mg & 4095;
      const long ga = ((long)bb << 12) + ((p + 32) & 4095);
      async16(A + ga * (long)K + kk, &lA[b][r * 32 + sp * 8]);
      async16(W + (size_t)(n0 + r) * K + kk, &lB[b][r * 32 + sp * 8]);
    }
  };

  const int NT = K >> 5;
  stage(0, 0);
  __syncthreads();
  int cur = 0;
  for (int kt = 0; kt < NT; ++kt) {
    if (kt + 1 < NT) stage(cur ^ 1, (kt + 1) << 5);
    bf16x8 fa[4], fb[4];
    #pragma unroll
    for (int t = 0; t < 4; ++t) {
      const int ra = wm + t * 16 + fr;
      fa[t] = *(const bf16x8*)&lA[cur][ra * 32 + ((hi ^ ((ra >> 1) & 3)) << 3)];
      const int rb = wn + t * 16 + fr;
      fb[t] = *(const bf16x8*)&lB[cur][rb * 32 + ((hi ^ ((rb >> 1) & 3)) << 3)];
    }
    #pragma unroll
    for (int mi = 0; mi < 4; ++mi)
      #pragma unroll
      for (int ni = 0; ni < 4; ++ni)
        acc[mi][ni] = __builtin_amdgcn_mfma_f32_16x16x32_bf16(fa[mi], fb[ni], acc[mi][ni], 0, 0, 0);
    __syncthreads();
    cur ^= 1;
  }

  const int lrow = hi * 4;
  #pragma unroll
  for (int mi = 0; mi < 4; ++mi) {
    #pragma unroll
    for (int ni = 0; ni < 4; ++ni) {
      const int n = n0 + wn + ni * 16 + fr;
      const int which = n >> 9, c = n & 511;
      const int hh = c >> 5, d = c & 31;
      const float bias = (which == 0) ? bias1[c] : (which == 2 ? bias2[c] : 0.f);
      #pragma unroll
      for (int r = 0; r < 4; ++r) {
        const int m = m0 + wm + mi * 16 + lrow + r;
        const int g = m >> 6, ii = m & 63;
        out[(size_t)which * 16777216 + (size_t)g * 32768 + hh * 2048 + ii * 32 + d] =
            f2bf(acc[mi][ni][r] + bias);
      }
    }
  }
}

// ---------------------------------------------------------------------------
// proj GEMM — standalone gemm_sm3-structure (128x128, BK=64, 2-phase dbuf)
// with attnT [16][32768][32] A-addressing. grid 1024 blocks (2 blocks/CU).
// ---------------------------------------------------------------------------
__global__ __launch_bounds__(256) void gemm_proj(
    const u16* __restrict__ A, const u16* __restrict__ W,
    const float* __restrict__ bias1,
    u16* __restrict__ out, int nby, int N, int K)
{
  __shared__ __attribute__((aligned(16))) u16 lA[2][8192];
  __shared__ __attribute__((aligned(16))) u16 lB[2][8192];
  const int tid = threadIdx.x;
  const int wid = tid >> 6;
  const int lane = tid & 63;
  const int q8 = (int)gridDim.x >> 3;
  const int swb = (blockIdx.x & 7) * q8 + (blockIdx.x >> 3);
  const int m0 = (swb / nby) * 128;
  const int n0 = (swb % nby) * 128;
  const int wm = (wid >> 1) * 64;
  const int wn = (wid & 1) * 64;
  f32x4 acc[4][4] = {};

  const int srow8 = lane >> 3;
  const int kel = ((lane & 7) ^ srow8) * 8;

  auto stage = [&](int b, int k0) {
    #pragma unroll
    for (int cc = 0; cc < 4; ++cc) {
      const int rb = wid * 32 + cc * 8;
      const int r = rb + srow8;
      const int kk = k0 + kel;
      async16(A + (size_t)(kk >> 5) * 1048576 + (size_t)(m0 + r) * 32 + (kk & 31),
              &lA[b][rb * 64]);
      async16(W + (size_t)(n0 + r) * K + kk, &lB[b][rb * 64]);
    }
  };

  const int NT = K >> 6;
  stage(0, 0);
  __syncthreads();
  int cur = 0;
  const int fr = lane & 15;
  const int hi = lane >> 4;
  const int fsw = fr & 7;
  for (int kt = 0; kt < NT; ++kt) {
    if (kt + 1 < NT) stage(cur ^ 1, (kt + 1) << 6);
    #pragma unroll
    for (int ks = 0; ks < 2; ++ks) {
      bf16x8 fa[4], fb[4];
      #pragma unroll
      for (int t = 0; t < 4; ++t) {
        const int ra = wm + t * 16 + fr;
        fa[t] = *(const bf16x8*)&lA[cur][ra * 64 + (((hi + 4 * ks) ^ fsw) << 3)];
        const int rbq = wn + t * 16 + fr;
        fb[t] = *(const bf16x8*)&lB[cur][rbq * 64 + (((hi + 4 * ks) ^ fsw) << 3)];
      }
      #pragma unroll
      for (int mi = 0; mi < 4; ++mi)
        #pragma unroll
        for (int ni = 0; ni < 4; ++ni)
          acc[mi][ni] = __builtin_amdgcn_mfma_f32_16x16x32_bf16(fa[mi], fb[ni], acc[mi][ni], 0, 0, 0);
    }
    __syncthreads();
    cur ^= 1;
  }

  const int lrow = (lane >> 4) * 4;
  #pragma unroll
  for (int mi = 0; mi < 4; ++mi)
    #pragma unroll
    for (int ni = 0; ni < 4; ++ni) {
      const int n = n0 + wn + ni * 16 + fr;
      #pragma unroll
      for (int r = 0; r < 4; ++r) {
        const int m = m0 + wm + mi * 16 + lrow + r;
        out[(size_t)m * N + n] = f2bf(acc[mi][ni][r] + bias1[n]);
      }
    }
}

// ---------------------------------------------------------------------------
// GEMM 256x256, BK=64, 8 waves, 4 phases/K-tile, counted vmcnt + T1 swizzle.
// MODE 2: fc1 (+bias+tanh-gelu)  (only instantiation)
// ---------------------------------------------------------------------------
template <int MODE>
__global__ __launch_bounds__(512, 2) void gemm_bt(
    const u16* __restrict__ A, const u16* __restrict__ W,
    const float* __restrict__ bias1, const float* __restrict__ bias2,
    u16* __restrict__ out, int nby, int N, int K)
{
  extern __shared__ __attribute__((aligned(16))) u16 smem[];
  const int tid = threadIdx.x;
  const int lane = tid & 63;
  const int wv = tid >> 6;
  const int q8 = (int)gridDim.x >> 3;
  const int swb = (blockIdx.x & 7) * q8 + (blockIdx.x >> 3);
  const int m0 = (swb / nby) * 256;
  const int n0 = (swb % nby) * 256;
  const int wm = (wv >> 2) * 128;
  const int wn = (wv & 3) * 64;
  const int fr = lane & 15;
  const int hi = lane >> 4;
  const int srow = tid >> 3;
  const int kb = (tid & 7) ^ (srow & 7);
  f32x4 acc[8][4] = {};

  auto stageA = [&](int buf, int k0, int i) {
    const int r = srow + (i << 6);
    async16(A + (size_t)(m0 + r) * K + k0 + kb * 8,
            smem + buf * 16384 + ((i << 9) + tid) * 8);
  };
  auto stageB = [&](int buf, int k0, int i) {
    const int r = srow + (i << 6);
    async16(W + (size_t)(n0 + r) * K + k0 + kb * 8,
            smem + 32768 + buf * 16384 + ((i << 9) + tid) * 8);
  };
  auto stage_part = [&](int buf, int k0, int part) {
    if (part == 0)      { stageB(buf, k0, 0); stageB(buf, k0, 1); }
    else if (part == 1) { stageB(buf, k0, 2); stageB(buf, k0, 3); }
    else if (part == 2) { stageA(buf, k0, 0); stageA(buf, k0, 2); }
    else                { stageA(buf, k0, 1); stageA(buf, k0, 3); }
  };

  auto phase_compute = [&](const u16* lac, const u16* lbc, int mh, int ks) {
    bf16x8 fa[4], fb[4];
    const int sw = hi + (ks << 2);
    #pragma unroll
    for (int mi = 0; mi < 4; ++mi) {
      const int r = wm + ((mh << 2) + mi) * 16 + fr;
      fa[mi] = *(const bf16x8*)&lac[r * 64 + ((sw ^ (r & 7)) << 3)];
    }
    #pragma unroll
    for (int ni = 0; ni < 4; ++ni) {
      const int r = wn + ni * 16 + fr;
      fb[ni] = *(const bf16x8*)&lbc[r * 64 + ((sw ^ (r & 7)) << 3)];
    }
    asm volatile("s_waitcnt lgkmcnt(0)" ::: "memory");
    __builtin_amdgcn_sched_barrier(0);
    __builtin_amdgcn_s_setprio(1);
    #pragma unroll
    for (int mi = 0; mi < 4; ++mi)
      #pragma unroll
      for (int ni = 0; ni < 4; ++ni)
        acc[(mh << 2) + mi][ni] = __builtin_amdgcn_mfma_f32_16x16x32_bf16(
            fa[mi], fb[ni], acc[(mh << 2) + mi][ni], 0, 0, 0);
    __builtin_amdgcn_s_setprio(0);
  };

  const int NT = K >> 6;
  stage_part(0, 0, 0); stage_part(0, 0, 1); stage_part(0, 0, 2); stage_part(0, 0, 3);
  int cur = 0;
  for (int kt = 0; kt < NT; ++kt) {
    const bool hn = (kt + 1) < NT;
    const int nk0 = (kt + 1) << 6;
    const u16* lac = smem + cur * 16384;
    const u16* lbc = smem + 32768 + cur * 16384;
    const int nb = cur ^ 1;
    asm volatile("s_waitcnt vmcnt(2)" ::: "memory");
    __builtin_amdgcn_s_barrier();
    if (hn) stage_part(nb, nk0, 0);
    phase_compute(lac, lbc, 0, 0);
    if (hn) { asm volatile("s_waitcnt vmcnt(2)" ::: "memory"); }
    else    { asm volatile("s_waitcnt vmcnt(0)" ::: "memory"); }
    __builtin_amdgcn_s_barrier();
    if (hn) stage_part(nb, nk0, 1);
    phase_compute(lac, lbc, 1, 0);
    if (hn) stage_part(nb, nk0, 2);
    phase_compute(lac, lbc, 0, 1);
    if (hn) stage_part(nb, nk0, 3);
    phase_compute(lac, lbc, 1, 1);
    cur ^= 1;
  }

  const int lrow = hi * 4;
  #pragma unroll
  for (int mi = 0; mi < 8; ++mi) {
    #pragma unroll
    for (int ni = 0; ni < 4; ++ni) {
      const int n = n0 + wn + ni * 16 + fr;
      #pragma unroll
      for (int r = 0; r < 4; ++r) {
        const int m = m0 + wm + mi * 16 + lrow + r;
        float v = acc[mi][ni][r];
        if constexpr (MODE == 2) {
          float t = v + bias1[n];
          float u = t * t;
          float z = t * (1.5957691216f + 0.0713548163f * u);
          float ge = t / (1.f + __expf(-z));
          out[(size_t)m * N + n] = f2bf(ge);
        } else {
          out[(size_t)m * N + n] = f2bf(v + bias1[n]);
        }
      }
    }
  }
}

// ---------------------------------------------------------------------------
// GEMM 128x128, BK=64, 2-phase dbuf — fc2 (+bias), + T1 swizzle.
// ---------------------------------------------------------------------------
__global__ __launch_bounds__(256) void gemm_sm3(
    const u16* __restrict__ A, const u16* __restrict__ W,
    const float* __restrict__ bias1,
    u16* __restrict__ out, int nby, int N, int K)
{
  __shared__ __attribute__((aligned(16))) u16 lA[2][8192];
  __shared__ __attribute__((aligned(16))) u16 lB[2][8192];
  const int tid = threadIdx.x;
  const int wid = tid >> 6;
  const int lane = tid & 63;
  const int q8 = (int)gridDim.x >> 3;
  const int swb = (blockIdx.x & 7) * q8 + (blockIdx.x >> 3);
  const int m0 = (swb / nby) * 128;
  const int n0 = (swb % nby) * 128;
  const int wm = (wid >> 1) * 64;
  const int wn = (wid & 1) * 64;
  f32x4 acc[4][4] = {};

  const int srow8 = lane >> 3;
  const int kel = ((lane & 7) ^ srow8) * 8;

  auto stage = [&](int b, int k0) {
    #pragma unroll
    for (int cc = 0; cc < 4; ++cc) {
      const int rb = wid * 32 + cc * 8;
      const int r = rb + srow8;
      async16(A + (size_t)(m0 + r) * K + k0 + kel, &lA[b][rb * 64]);
      async16(W + (size_t)(n0 + r) * K + k0 + kel, &lB[b][rb * 64]);
    }
  };

  const int NT = K >> 6;
  stage(0, 0);
  __syncthreads();
  int cur = 0;
  const int fr = lane & 15;
  const int hi = lane >> 4;
  const int fsw = fr & 7;
  for (int kt = 0; kt < NT; ++kt) {
    if (kt + 1 < NT) stage(cur ^ 1, (kt + 1) << 6);
    #pragma unroll
    for (int ks = 0; ks < 2; ++ks) {
      bf16x8 fa[4], fb[4];
      #pragma unroll
      for (int t = 0; t < 4; ++t) {
        const int ra = wm + t * 16 + fr;
        fa[t] = *(const bf16x8*)&lA[cur][ra * 64 + (((hi + 4 * ks) ^ fsw) << 3)];
        const int rbq = wn + t * 16 + fr;
        fb[t] = *(const bf16x8*)&lB[cur][rbq * 64 + (((hi + 4 * ks) ^ fsw) << 3)];
      }
      #pragma unroll
      for (int mi = 0; mi < 4; ++mi)
        #pragma unroll
        for (int ni = 0; ni < 4; ++ni)
          acc[mi][ni] = __builtin_amdgcn_mfma_f32_16x16x32_bf16(fa[mi], fb[ni], acc[mi][ni], 0, 0, 0);
    }
    __syncthreads();
    cur ^= 1;
  }

  const int lrow = (lane >> 4) * 4;
  #pragma unroll
  for (int mi = 0; mi < 4; ++mi)
    #pragma unroll
    for (int ni = 0; ni < 4; ++ni) {
      const int n = n0 + wn + ni * 16 + fr;
      #pragma unroll
      for (int r = 0; r < 4; ++r) {
        const int m = m0 + wm + mi * 16 + lrow + r;
        out[(size_t)m * N + n] = f2bf(acc[mi][ni][r] + bias1[n]);
      }
    }
}

// ---------------------------------------------------------------------------
// Attention (MFMA): 512 blocks x 4 waves; wave = (window gg, heads w*4+t).
// vt/pl are PER-WAVE buffers -> no __syncthreads (r13-proven).
// ---------------------------------------------------------------------------
__global__ __launch_bounds__(256) void attn_kernel(
    const u16* __restrict__ qkv, const float* __restrict__ ls,
    const float* __restrict__ btbl, u16* __restrict__ attnT)
{
  const int gg = blockIdx.x;
  const int w = threadIdx.x >> 6;
  const int lane = threadIdx.x & 63;
  __shared__ __attribute__((aligned(16))) u16 vt[4][2048];
  __shared__ __attribute__((aligned(16))) u16 pl[4][4096];
  const bool maskw = ((gg & 63) == 63);
  const int fr = lane & 15;
  const int fkq = (lane >> 4) * 8;
  const int crow = (lane >> 4) * 4;

  for (int t = 0; t < 4; ++t) {
    const int h = w * 4 + t;
    const size_t bgh = (size_t)gg * 32768 + (size_t)h * 2048;

    {
      const u16x8* vp = (const u16x8*)(qkv + 33554432 + bgh + (size_t)lane * 32);
      #pragma unroll
      for (int c = 0; c < 4; ++c) {
        u16x8 vr = vp[c];
        #pragma unroll
        for (int e = 0; e < 8; ++e) {
          const int d = c * 8 + e;
          const int addr = d * 64 + (((lane >> 3) ^ (d & 7)) << 3) + (lane & 7);
          vt[w][addr] = vr[e];
        }
      }
    }

    const float scale = __expf(fminf(ls[h], 4.6051701859880914f));
    bf16x8 qa[4], kb[4];
    #pragma unroll
    for (int mi = 0; mi < 4; ++mi) {
      u16x8 raw = *(const u16x8*)(qkv + bgh + (size_t)(mi * 16 + fr) * 32 + fkq);
      float f[8]; float ssum = 0.f;
      #pragma unroll
      for (int e = 0; e < 8; ++e) { f[e] = b2f(raw[e]); ssum += f[e] * f[e]; }
      ssum += __shfl_xor(ssum, 16); ssum += __shfl_xor(ssum, 32);
      const float mul = scale / fmaxf(sqrtf(ssum), 1e-12f);
      u16x8 tmp;
      #pragma unroll
      for (int e = 0; e < 8; ++e) tmp[e] = f2bf(f[e] * mul);
      qa[mi] = __builtin_bit_cast(bf16x8, tmp);
    }
    #pragma unroll
    for (int ni = 0; ni < 4; ++ni) {
      u16x8 raw = *(const u16x8*)(qkv + 16777216 + bgh + (size_t)(ni * 16 + fr) * 32 + fkq);
      float f[8]; float ssum = 0.f;
      #pragma unroll
      for (int e = 0; e < 8; ++e) { f[e] = b2f(raw[e]); ssum += f[e] * f[e]; }
      ssum += __shfl_xor(ssum, 16); ssum += __shfl_xor(ssum, 32);
      const float mul = 1.f / fmaxf(sqrtf(ssum), 1e-12f);
      u16x8 tmp;
      #pragma unroll
      for (int e = 0; e < 8; ++e) tmp[e] = f2bf(f[e] * mul);
      kb[ni] = __builtin_bit_cast(bf16x8, tmp);
    }

    f32x4 s[4][4] = {};
    __builtin_amdgcn_s_setprio(1);
    #pragma unroll
    for (int mi = 0; mi < 4; ++mi)
      #pragma unroll
      for (int ni = 0; ni < 4; ++ni)
        s[mi][ni] = __builtin_amdgcn_mfma_f32_16x16x32_bf16(qa[mi], kb[ni], s[mi][ni], 0, 0, 0);
    __builtin_amdgcn_s_setprio(0);

    const float mh = scale + 16.f;
    float inv_[4][4];
    #pragma unroll
    for (int mi = 0; mi < 4; ++mi) {
      #pragma unroll
      for (int r = 0; r < 4; ++r) {
        const int row = mi * 16 + crow + r;
        float es = 0.f;
        #pragma unroll
        for (int ni = 0; ni < 4; ++ni) {
          const int col = ni * 16 + fr;
          float sv = s[mi][ni][r] + btbl[h * 4096 + row * 64 + col];
          if (maskw && ((row < 32) != (col < 32))) sv -= 100.f;
          const float e = __expf(sv - mh);
          s[mi][ni][r] = e;
          es += e;
        }
        es += __shfl_xor(es, 1); es += __shfl_xor(es, 2);
        es += __shfl_xor(es, 4); es += __shfl_xor(es, 8);
        inv_[mi][r] = 1.f / fmaxf(es, 1e-37f);
      }
    }

    #pragma unroll
    for (int mi = 0; mi < 4; ++mi)
      #pragma unroll
      for (int r = 0; r < 4; ++r) {
        const int row = mi * 16 + crow + r;
        #pragma unroll
        for (int ni = 0; ni < 4; ++ni) {
          const int col = ni * 16 + fr;
          const int addr = row * 64 + (((col >> 3) ^ (row & 7)) << 3) + (col & 7);
          pl[w][addr] = f2bf(s[mi][ni][r]);
        }
      }

    f32x4 o[4][2] = {};
    #pragma unroll
    for (int ks = 0; ks < 2; ++ks) {
      bf16x8 vbf[2];
      #pragma unroll
      for (int np = 0; np < 2; ++np) {
        const int d = np * 16 + fr;
        const int jb = (lane >> 4) + ks * 4;
        vbf[np] = *(const bf16x8*)&vt[w][d * 64 + ((jb ^ (d & 7)) << 3)];
      }
      __builtin_amdgcn_s_setprio(1);
      #pragma unroll
      for (int mp = 0; mp < 4; ++mp) {
        const int row = mp * 16 + fr;
        const int cb = (lane >> 4) + ks * 4;
        bf16x8 paf = *(const bf16x8*)&pl[w][row * 64 + ((cb ^ (row & 7)) << 3)];
        o[mp][0] = __builtin_amdgcn_mfma_f32_16x16x32_bf16(paf, vbf[0], o[mp][0], 0, 0, 0);
        o[mp][1] = __builtin_amdgcn_mfma_f32_16x16x32_bf16(paf, vbf[1], o[mp][1], 0, 0, 0);
      }
      __builtin_amdgcn_s_setprio(0);
    }

    #pragma unroll
    for (int mp = 0; mp < 4; ++mp)
      #pragma unroll
      for (int r = 0; r < 4; ++r) {
        const int row = mp * 16 + crow + r;
        const float iv = inv_[mp][r];
        u16* op = attnT + (size_t)h * 1048576 + (size_t)(gg * 64 + row) * 32;
        op[fr]      = f2bf(o[mp][0][r] * iv);
        op[16 + fr] = f2bf(o[mp][1][r] * iv);
      }
  }
}

// ---------------------------------------------------------------------------
// LN1 (wave-per-row): x1h = bf16( x + LN(roll_back(proj_out)) )
// ---------------------------------------------------------------------------
__global__ __launch_bounds__(256) void ln1_kernel(
    const u16* __restrict__ proj, const float* __restrict__ x,
    const float* __restrict__ w, const float* __restrict__ bb,
    u16* __restrict__ x1h)
{
  const int row = blockIdx.x * 4 + (threadIdx.x >> 6);
  const int lane = threadIdx.x & 63;
  const int b = row >> 12, l = row & 4095;
  const int p = (l - 32) & 4095;
  const size_t srow = (((size_t)b << 12) + p) << 9;
  const int c0 = lane * 8;
  u16x8 pv = *(const u16x8*)(proj + srow + c0);
  float v[8]; float s = 0.f, ss = 0.f;
  #pragma unroll
  for (int e = 0; e < 8; ++e) { v[e] = b2f(pv[e]); s += v[e]; ss += v[e] * v[e]; }
  #pragma unroll
  for (int o = 32; o > 0; o >>= 1) { s += __shfl_xor(s, o); ss += __shfl_xor(ss, o); }
  const float mean = s * (1.f / 512.f);
  const float var = ss * (1.f / 512.f) - mean * mean;
  const float rstd = rsqrtf(var + 1e-5f);
  const size_t orow = (size_t)row << 9;
  float4 x0 = *(const float4*)(x + orow + c0);
  float4 x1 = *(const float4*)(x + orow + c0 + 4);
  const float xs[8] = {x0.x, x0.y, x0.z, x0.w, x1.x, x1.y, x1.z, x1.w};
  u16x8 ho;
  #pragma unroll
  for (int e = 0; e < 8; ++e)
    ho[e] = f2bf(xs[e] + (v[e] - mean) * rstd * w[c0 + e] + bb[c0 + e]);
  *(u16x8*)(x1h + orow + c0) = ho;
}

// ---------------------------------------------------------------------------
// LN2 (wave-per-row, per half): out = f32( x1 + LN(fc2_out) )
// ---------------------------------------------------------------------------
__global__ __launch_bounds__(256) void ln2_kernel(
    const u16* __restrict__ fc2, const u16* __restrict__ x1h,
    const float* __restrict__ w, const float* __restrict__ bb,
    float* __restrict__ out)
{
  const int row = blockIdx.x * 4 + (threadIdx.x >> 6);
  const int lane = threadIdx.x & 63;
  const size_t r512 = (size_t)row << 9;
  const int c0 = lane * 8;
  u16x8 pv = *(const u16x8*)(fc2 + r512 + c0);
  float v[8]; float s = 0.f, ss = 0.f;
  #pragma unroll
  for (int e = 0; e < 8; ++e) { v[e] = b2f(pv[e]); s += v[e]; ss += v[e] * v[e]; }
  #pragma unroll
  for (int o = 32; o > 0; o >>= 1) { s += __shfl_xor(s, o); ss += __shfl_xor(ss, o); }
  const float mean = s * (1.f / 512.f);
  const float var = ss * (1.f / 512.f) - mean * mean;
  const float rstd = rsqrtf(var + 1e-5f);
  u16x8 xv = *(const u16x8*)(x1h + r512 + c0);
  float r[8];
  #pragma unroll
  for (int e = 0; e < 8; ++e)
    r[e] = b2f(xv[e]) + (v[e] - mean) * rstd * w[c0 + e] + bb[c0 + e];
  float4 o0, o1;
  o0.x = r[0]; o0.y = r[1]; o0.z = r[2]; o0.w = r[3];
  o1.x = r[4]; o1.y = r[5]; o1.z = r[6]; o1.w = r[7];
  *(float4*)(out + r512 + c0) = o0;
  *(float4*)(out + r512 + c0 + 4) = o1;
}

// ---------------------------------------------------------------------------
extern "C" void kernel_launch(void* const* d_in, const int* in_sizes, int n_in,
                              void* d_out, int out_size, void* d_ws, size_t ws_size,
                              hipStream_t stream) {
  const float* x        = (const float*)d_in[0];
  const float* qkv_w    = (const float*)d_in[1];
  const float* q_bias   = (const float*)d_in[2];
  const float* v_bias   = (const float*)d_in[3];
  const float* lscale   = (const float*)d_in[4];
  const float* cpb_w1   = (const float*)d_in[5];
  const float* cpb_b1   = (const float*)d_in[6];
  const float* cpb_w2   = (const float*)d_in[7];
  const float* proj_w   = (const float*)d_in[8];
  const float* proj_b   = (const float*)d_in[9];
  const float* n1w      = (const float*)d_in[10];
  const float* n1b      = (const float*)d_in[11];
  const float* n2w      = (const float*)d_in[12];
  const float* n2b      = (const float*)d_in[13];
  const float* fc1_w    = (const float*)d_in[14];
  const float* fc1_b    = (const float*)d_in[15];
  const float* fc2_w    = (const float*)d_in[16];
  const float* fc2_b    = (const float*)d_in[17];

  if (ws_size < 134217728u) return;
  char* ws = (char*)d_ws;
  u16* wqkv   = (u16*)(ws + 0);
  u16* wproj  = (u16*)(ws + 1572864);
  u16* wfc1   = (u16*)(ws + 2097152);
  u16* wfc2   = (u16*)(ws + 4194304);
  float* btbl = (float*)(ws + 6291456);
  u16* qkv    = (u16*)(ws + 6553600);
  u16* projo  = (u16*)(ws + 6553600);
  u16* hbuf   = (u16*)(ws + 6553600);
  u16* fc2oh  = (u16*)(ws + 73662464);
  u16* x1h    = (u16*)(ws + 94371840);
  float* tbl  = (float*)(ws + 127926272);
  u16* xbf   = (u16*)d_out;
  u16* attnT = (u16*)d_out;
  float* out = (float*)d_out;

  hipFuncSetAttribute((const void*)gemm_bt<2>, hipFuncAttributeMaxDynamicSharedMemorySize, 131072);

  cvt_all_kernel<<<19456, 256, 0, stream>>>(
      x, qkv_w, proj_w, fc1_w, fc2_w, xbf, wqkv, wproj, wfc1, wfc2);
  cpb1_kernel<<<dim3(127, 16), 64, 0, stream>>>(cpb_w1, cpb_b1, cpb_w2, tbl);
  cpb2_kernel<<<16, 256, 0, stream>>>(tbl, btbl);

  gemm_qkv<<<3072, 256, 0, stream>>>(
      xbf, wqkv, q_bias, v_bias, qkv, 12, 1536, 512);
  attn_kernel<<<512, 256, 0, stream>>>(qkv, lscale, btbl, attnT);
  gemm_proj<<<1024, 256, 0, stream>>>(
      attnT, wproj, proj_b, projo, 4, 512, 512);
  ln1_kernel<<<8192, 256, 0, stream>>>(projo, x, n1w, n1b, x1h);
  for (int half = 0; half < 2; ++half) {
    const u16* a2 = x1h + (size_t)half * 8388608;
    gemm_bt<2><<<512, 512, 131072, stream>>>(
        a2, wfc1, fc1_b, nullptr, hbuf, 8, 2048, 512);
    gemm_sm3<<<512, 256, 0, stream>>>(
        hbuf, wfc2, fc2_b, fc2oh, 4, 512, 2048);
    ln2_kernel<<<4096, 256, 0, stream>>>(
        fc2oh, a2, n2w, n2b, out + (size_t)half * 8388608);
  }
}

// Round 15
// 397.110 us; speedup vs baseline: 1.0707x; 1.0707x over previous
//
#include <hip/hip_runtime.h>
#include <hip/hip_bf16.h>
#include <math.h>

typedef unsigned short u16;
typedef __bf16 bf16x8 __attribute__((ext_vector_type(8)));
typedef float f32x4 __attribute__((ext_vector_type(4)));
typedef unsigned short u16x8 __attribute__((ext_vector_type(8)));
typedef unsigned short u16x4 __attribute__((ext_vector_type(4)));
typedef unsigned short u16x2 __attribute__((ext_vector_type(2)));

#define DEV static __device__ __forceinline__

DEV float b2f(u16 v) { unsigned u = ((unsigned)v) << 16; return __builtin_bit_cast(float, u); }
DEV u16 f2bf(float f) {
  unsigned u = __builtin_bit_cast(unsigned, f);
  u += 0x7fffu + ((u >> 16) & 1u);
  return (u16)(u >> 16);
}

DEV void async16(const void* g, void* l) {
  __builtin_amdgcn_global_load_lds(
      (const __attribute__((address_space(1))) void*)g,
      (__attribute__((address_space(3))) void*)l, 16, 0, 0);
}

// ---------------------------------------------------------------------------
// One-shot f32 -> bf16 conversion of x + all 4 weight matrices.
// ---------------------------------------------------------------------------
__global__ __launch_bounds__(256) void cvt_all_kernel(
    const float* __restrict__ x,  const float* __restrict__ wq,
    const float* __restrict__ wp, const float* __restrict__ w1,
    const float* __restrict__ w2,
    u16* __restrict__ dx, u16* __restrict__ dq, u16* __restrict__ dp,
    u16* __restrict__ d1, u16* __restrict__ d2)
{
  const int i = blockIdx.x * 256 + threadIdx.x;
  const float* s; u16* d; int off;
  if (i < 4194304)      { s = x;  d = dx; off = i; }
  else if (i < 4390912) { s = wq; d = dq; off = i - 4194304; }
  else if (i < 4456448) { s = wp; d = dp; off = i - 4390912; }
  else if (i < 4718592) { s = w1; d = d1; off = i - 4456448; }
  else if (i < 4980736) { s = w2; d = d2; off = i - 4718592; }
  else return;
  float4 v = ((const float4*)s)[off];
  u16x4 o;
  o[0] = f2bf(v.x); o[1] = f2bf(v.y); o[2] = f2bf(v.z); o[3] = f2bf(v.w);
  ((u16x4*)d)[off] = o;
}

// ---------------------------------------------------------------------------
// CPB stage 1 + stage 2
// ---------------------------------------------------------------------------
__global__ __launch_bounds__(64) void cpb1_kernel(
    const float* __restrict__ w1, const float* __restrict__ b1,
    const float* __restrict__ w2, float* __restrict__ tbl)
{
  const int r = blockIdx.x, h = blockIdx.y;
  const int lane = threadIdx.x;
  float rv = (float)(r - 63) * (8.0f / 63.0f);
  float sgn = (rv > 0.f) ? 1.f : ((rv < 0.f) ? -1.f : 0.f);
  float t = sgn * log2f(fabsf(rv) + 1.f) * (1.f / 3.f);
  float part = 0.f;
  for (int k = lane; k < 512; k += 64) {
    float hid = fmaxf(t * w1[k] + b1[k], 0.f);
    part += hid * w2[h * 512 + k];
  }
  #pragma unroll
  for (int o = 32; o > 0; o >>= 1) part += __shfl_down(part, o);
  if (lane == 0) tbl[r * 16 + h] = part;
}

__global__ __launch_bounds__(256) void cpb2_kernel(
    const float* __restrict__ tbl, float* __restrict__ btbl)
{
  const int h = blockIdx.x;
  for (int idx = threadIdx.x; idx < 4096; idx += 256) {
    int i = idx >> 6, j = idx & 63;
    float v = tbl[(i - j + 63) * 16 + h];
    btbl[h * 4096 + idx] = 16.f / (1.f + __expf(-v));
  }
}

// ---------------------------------------------------------------------------
// qkv GEMM — r11/r13 m97-structure (single 16KB LDS buffer, BK=32).
// ---------------------------------------------------------------------------
__global__ __launch_bounds__(256, 4) void gemm_qkv(
    const u16* __restrict__ A, const u16* __restrict__ W,
    const float* __restrict__ bias1, const float* __restrict__ bias2,
    u16* __restrict__ out, int nby, int N, int K)
{
  __shared__ __attribute__((aligned(16))) u16 lA[4096];   // [128][32] swz
  __shared__ __attribute__((aligned(16))) u16 lB[4096];
  const int tid = threadIdx.x;
  const int lane = tid & 63;
  const int wv = tid >> 6;
  const int q8 = (int)gridDim.x >> 3;
  const int swb = (blockIdx.x & 7) * q8 + (blockIdx.x >> 3);
  const int m0 = (swb / nby) * 128;
  const int n0 = (swb % nby) * 128;
  const int wm = (wv >> 1) * 64;
  const int wn = (wv & 1) * 64;
  const int fr = lane & 15;
  const int hi = lane >> 4;
  const int sr = tid >> 2;       // 0..63
  const int sp = tid & 3;
  f32x4 acc[4][4] = {};

  for (int k0 = 0; k0 < K; k0 += 32) {
    #pragma unroll
    for (int i = 0; i < 2; ++i) {
      const int r = i * 64 + sr;
      const int kk = k0 + ((sp ^ ((r >> 1) & 3)) << 3);
      const int mg = m0 + r;
      const int bb = mg >> 12;
      const int p = mg & 4095;
      const long ga = ((long)bb << 12) + ((p + 32) & 4095);
      async16(A + ga * (long)K + kk, lA + r * 32 + sp * 8);
      async16(W + (size_t)(n0 + r) * K + kk, lB + r * 32 + sp * 8);
    }
    __syncthreads();
    bf16x8 fa[4], fb[4];
    #pragma unroll
    for (int t = 0; t < 4; ++t) {
      const int ra = wm + t * 16 + fr;
      fa[t] = *(const bf16x8*)&lA[ra * 32 + ((hi ^ ((ra >> 1) & 3)) << 3)];
      const int rb = wn + t * 16 + fr;
      fb[t] = *(const bf16x8*)&lB[rb * 32 + ((hi ^ ((rb >> 1) & 3)) << 3)];
    }
    #pragma unroll
    for (int mi = 0; mi < 4; ++mi)
      #pragma unroll
      for (int ni = 0; ni < 4; ++ni)
        acc[mi][ni] = __builtin_amdgcn_mfma_f32_16x16x32_bf16(fa[mi], fb[ni], acc[mi][ni], 0, 0, 0);
    __syncthreads();
  }

  const int lrow = hi * 4;
  #pragma unroll
  for (int mi = 0; mi < 4; ++mi) {
    #pragma unroll
    for (int ni = 0; ni < 4; ++ni) {
      const int n = n0 + wn + ni * 16 + fr;
      const int which = n >> 9, c = n & 511;
      const int hh = c >> 5, d = c & 31;
      const float bias = (which == 0) ? bias1[c] : (which == 2 ? bias2[c] : 0.f);
      #pragma unroll
      for (int r = 0; r < 4; ++r) {
        const int m = m0 + wm + mi * 16 + lrow + r;
        const int g = m >> 6, ii = m & 63;
        out[(size_t)which * 16777216 + (size_t)g * 32768 + hh * 2048 + ii * 32 + d] =
            f2bf(acc[mi][ni][r] + bias);
      }
    }
  }
}

// ---------------------------------------------------------------------------
// GEMM 256x256, BK=64, 8 waves, 4 phases/K-tile, counted vmcnt + T1 swizzle.
// MODE 1: proj (A = attnU [8][32768][64] head-pair layout; +bias)
// MODE 2: fc1 (+bias+tanh-gelu)
// ---------------------------------------------------------------------------
template <int MODE>
__global__ __launch_bounds__(512, 2) void gemm_bt(
    const u16* __restrict__ A, const u16* __restrict__ W,
    const float* __restrict__ bias1, const float* __restrict__ bias2,
    u16* __restrict__ out, int nby, int N, int K)
{
  extern __shared__ __attribute__((aligned(16))) u16 smem[];
  const int tid = threadIdx.x;
  const int lane = tid & 63;
  const int wv = tid >> 6;
  const int q8 = (int)gridDim.x >> 3;
  const int swb = (blockIdx.x & 7) * q8 + (blockIdx.x >> 3);
  const int m0 = (swb / nby) * 256;
  const int n0 = (swb % nby) * 256;
  const int wm = (wv >> 2) * 128;
  const int wn = (wv & 3) * 64;
  const int fr = lane & 15;
  const int hi = lane >> 4;
  const int srow = tid >> 3;
  const int kb = (tid & 7) ^ (srow & 7);
  f32x4 acc[8][4] = {};

  auto stageA = [&](int buf, int k0, int i) {
    const int r = srow + (i << 6);
    const u16* src;
    if constexpr (MODE == 1) {
      // attnU head-pair layout: row's 64 elems contiguous (kk&63 == kb*8)
      src = A + (size_t)(k0 >> 6) * 2097152 + (size_t)(m0 + r) * 64 + kb * 8;
    } else {
      src = A + (size_t)(m0 + r) * K + k0 + kb * 8;
    }
    async16(src, smem + buf * 16384 + ((i << 9) + tid) * 8);
  };
  auto stageB = [&](int buf, int k0, int i) {
    const int r = srow + (i << 6);
    async16(W + (size_t)(n0 + r) * K + k0 + kb * 8,
            smem + 32768 + buf * 16384 + ((i << 9) + tid) * 8);
  };
  auto stage_part = [&](int buf, int k0, int part) {
    if (part == 0)      { stageB(buf, k0, 0); stageB(buf, k0, 1); }
    else if (part == 1) { stageB(buf, k0, 2); stageB(buf, k0, 3); }
    else if (part == 2) { stageA(buf, k0, 0); stageA(buf, k0, 2); }
    else                { stageA(buf, k0, 1); stageA(buf, k0, 3); }
  };

  auto phase_compute = [&](const u16* lac, const u16* lbc, int mh, int ks) {
    bf16x8 fa[4], fb[4];
    const int sw = hi + (ks << 2);
    #pragma unroll
    for (int mi = 0; mi < 4; ++mi) {
      const int r = wm + ((mh << 2) + mi) * 16 + fr;
      fa[mi] = *(const bf16x8*)&lac[r * 64 + ((sw ^ (r & 7)) << 3)];
    }
    #pragma unroll
    for (int ni = 0; ni < 4; ++ni) {
      const int r = wn + ni * 16 + fr;
      fb[ni] = *(const bf16x8*)&lbc[r * 64 + ((sw ^ (r & 7)) << 3)];
    }
    asm volatile("s_waitcnt lgkmcnt(0)" ::: "memory");
    __builtin_amdgcn_sched_barrier(0);
    __builtin_amdgcn_s_setprio(1);
    #pragma unroll
    for (int mi = 0; mi < 4; ++mi)
      #pragma unroll
      for (int ni = 0; ni < 4; ++ni)
        acc[(mh << 2) + mi][ni] = __builtin_amdgcn_mfma_f32_16x16x32_bf16(
            fa[mi], fb[ni], acc[(mh << 2) + mi][ni], 0, 0, 0);
    __builtin_amdgcn_s_setprio(0);
  };

  const int NT = K >> 6;
  stage_part(0, 0, 0); stage_part(0, 0, 1); stage_part(0, 0, 2); stage_part(0, 0, 3);
  int cur = 0;
  for (int kt = 0; kt < NT; ++kt) {
    const bool hn = (kt + 1) < NT;
    const int nk0 = (kt + 1) << 6;
    const u16* lac = smem + cur * 16384;
    const u16* lbc = smem + 32768 + cur * 16384;
    const int nb = cur ^ 1;
    asm volatile("s_waitcnt vmcnt(2)" ::: "memory");
    __builtin_amdgcn_s_barrier();
    if (hn) stage_part(nb, nk0, 0);
    phase_compute(lac, lbc, 0, 0);
    if (hn) { asm volatile("s_waitcnt vmcnt(2)" ::: "memory"); }
    else    { asm volatile("s_waitcnt vmcnt(0)" ::: "memory"); }
    __builtin_amdgcn_s_barrier();
    if (hn) stage_part(nb, nk0, 1);
    phase_compute(lac, lbc, 1, 0);
    if (hn) stage_part(nb, nk0, 2);
    phase_compute(lac, lbc, 0, 1);
    if (hn) stage_part(nb, nk0, 3);
    phase_compute(lac, lbc, 1, 1);
    cur ^= 1;
  }

  const int lrow = hi * 4;
  #pragma unroll
  for (int mi = 0; mi < 8; ++mi) {
    #pragma unroll
    for (int ni = 0; ni < 4; ++ni) {
      const int n = n0 + wn + ni * 16 + fr;
      #pragma unroll
      for (int r = 0; r < 4; ++r) {
        const int m = m0 + wm + mi * 16 + lrow + r;
        float v = acc[mi][ni][r];
        if constexpr (MODE == 2) {
          float t = v + bias1[n];
          float u = t * t;
          float z = t * (1.5957691216f + 0.0713548163f * u);
          float ge = t / (1.f + __expf(-z));
          out[(size_t)m * N + n] = f2bf(ge);
        } else {
          out[(size_t)m * N + n] = f2bf(v + bias1[n]);
        }
      }
    }
  }
}

// ---------------------------------------------------------------------------
// GEMM 128x128, BK=64, 2-phase dbuf — fc2 (+bias), + T1 swizzle.
// ---------------------------------------------------------------------------
__global__ __launch_bounds__(256) void gemm_sm3(
    const u16* __restrict__ A, const u16* __restrict__ W,
    const float* __restrict__ bias1,
    u16* __restrict__ out, int nby, int N, int K)
{
  __shared__ __attribute__((aligned(16))) u16 lA[2][8192];
  __shared__ __attribute__((aligned(16))) u16 lB[2][8192];
  const int tid = threadIdx.x;
  const int wid = tid >> 6;
  const int lane = tid & 63;
  const int q8 = (int)gridDim.x >> 3;
  const int swb = (blockIdx.x & 7) * q8 + (blockIdx.x >> 3);
  const int m0 = (swb / nby) * 128;
  const int n0 = (swb % nby) * 128;
  const int wm = (wid >> 1) * 64;
  const int wn = (wid & 1) * 64;
  f32x4 acc[4][4] = {};

  const int srow8 = lane >> 3;
  const int kel = ((lane & 7) ^ srow8) * 8;

  auto stage = [&](int b, int k0) {
    #pragma unroll
    for (int cc = 0; cc < 4; ++cc) {
      const int rb = wid * 32 + cc * 8;
      const int r = rb + srow8;
      async16(A + (size_t)(m0 + r) * K + k0 + kel, &lA[b][rb * 64]);
      async16(W + (size_t)(n0 + r) * K + k0 + kel, &lB[b][rb * 64]);
    }
  };

  const int NT = K >> 6;
  stage(0, 0);
  __syncthreads();
  int cur = 0;
  const int fr = lane & 15;
  const int hi = lane >> 4;
  const int fsw = fr & 7;
  for (int kt = 0; kt < NT; ++kt) {
    if (kt + 1 < NT) stage(cur ^ 1, (kt + 1) << 6);
    #pragma unroll
    for (int ks = 0; ks < 2; ++ks) {
      bf16x8 fa[4], fb[4];
      #pragma unroll
      for (int t = 0; t < 4; ++t) {
        const int ra = wm + t * 16 + fr;
        fa[t] = *(const bf16x8*)&lA[cur][ra * 64 + (((hi + 4 * ks) ^ fsw) << 3)];
        const int rbq = wn + t * 16 + fr;
        fb[t] = *(const bf16x8*)&lB[cur][rbq * 64 + (((hi + 4 * ks) ^ fsw) << 3)];
      }
      #pragma unroll
      for (int mi = 0; mi < 4; ++mi)
        #pragma unroll
        for (int ni = 0; ni < 4; ++ni)
          acc[mi][ni] = __builtin_amdgcn_mfma_f32_16x16x32_bf16(fa[mi], fb[ni], acc[mi][ni], 0, 0, 0);
    }
    __syncthreads();
    cur ^= 1;
  }

  const int lrow = (lane >> 4) * 4;
  #pragma unroll
  for (int mi = 0; mi < 4; ++mi)
    #pragma unroll
    for (int ni = 0; ni < 4; ++ni) {
      const int n = n0 + wn + ni * 16 + fr;
      #pragma unroll
      for (int r = 0; r < 4; ++r) {
        const int m = m0 + wm + mi * 16 + lrow + r;
        out[(size_t)m * N + n] = f2bf(acc[mi][ni][r] + bias1[n]);
      }
    }
}

// ---------------------------------------------------------------------------
// Attention (MFMA): 512 blocks x 4 waves; wave = (window gg, heads w*4+t).
// vt/pl per-wave -> no __syncthreads (r13-proven). Output in head-pair
// layout attnU[8][32768][64]: elem (m,h,d) at ((h>>1)*32768+m)*64+(h&1)*32+d.
// ---------------------------------------------------------------------------
__global__ __launch_bounds__(256) void attn_kernel(
    const u16* __restrict__ qkv, const float* __restrict__ ls,
    const float* __restrict__ btbl, u16* __restrict__ attnU)
{
  const int gg = blockIdx.x;
  const int w = threadIdx.x >> 6;
  const int lane = threadIdx.x & 63;
  __shared__ __attribute__((aligned(16))) u16 vt[4][2048];
  __shared__ __attribute__((aligned(16))) u16 pl[4][4096];
  const bool maskw = ((gg & 63) == 63);
  const int fr = lane & 15;
  const int fkq = (lane >> 4) * 8;
  const int crow = (lane >> 4) * 4;

  for (int t = 0; t < 4; ++t) {
    const int h = w * 4 + t;
    const size_t bgh = (size_t)gg * 32768 + (size_t)h * 2048;

    {
      const u16x8* vp = (const u16x8*)(qkv + 33554432 + bgh + (size_t)lane * 32);
      #pragma unroll
      for (int c = 0; c < 4; ++c) {
        u16x8 vr = vp[c];
        #pragma unroll
        for (int e = 0; e < 8; ++e) {
          const int d = c * 8 + e;
          const int addr = d * 64 + (((lane >> 3) ^ (d & 7)) << 3) + (lane & 7);
          vt[w][addr] = vr[e];
        }
      }
    }

    const float scale = __expf(fminf(ls[h], 4.6051701859880914f));
    bf16x8 qa[4], kb[4];
    #pragma unroll
    for (int mi = 0; mi < 4; ++mi) {
      u16x8 raw = *(const u16x8*)(qkv + bgh + (size_t)(mi * 16 + fr) * 32 + fkq);
      float f[8]; float ssum = 0.f;
      #pragma unroll
      for (int e = 0; e < 8; ++e) { f[e] = b2f(raw[e]); ssum += f[e] * f[e]; }
      ssum += __shfl_xor(ssum, 16); ssum += __shfl_xor(ssum, 32);
      const float mul = scale / fmaxf(sqrtf(ssum), 1e-12f);
      u16x8 tmp;
      #pragma unroll
      for (int e = 0; e < 8; ++e) tmp[e] = f2bf(f[e] * mul);
      qa[mi] = __builtin_bit_cast(bf16x8, tmp);
    }
    #pragma unroll
    for (int ni = 0; ni < 4; ++ni) {
      u16x8 raw = *(const u16x8*)(qkv + 16777216 + bgh + (size_t)(ni * 16 + fr) * 32 + fkq);
      float f[8]; float ssum = 0.f;
      #pragma unroll
      for (int e = 0; e < 8; ++e) { f[e] = b2f(raw[e]); ssum += f[e] * f[e]; }
      ssum += __shfl_xor(ssum, 16); ssum += __shfl_xor(ssum, 32);
      const float mul = 1.f / fmaxf(sqrtf(ssum), 1e-12f);
      u16x8 tmp;
      #pragma unroll
      for (int e = 0; e < 8; ++e) tmp[e] = f2bf(f[e] * mul);
      kb[ni] = __builtin_bit_cast(bf16x8, tmp);
    }

    f32x4 s[4][4] = {};
    __builtin_amdgcn_s_setprio(1);
    #pragma unroll
    for (int mi = 0; mi < 4; ++mi)
      #pragma unroll
      for (int ni = 0; ni < 4; ++ni)
        s[mi][ni] = __builtin_amdgcn_mfma_f32_16x16x32_bf16(qa[mi], kb[ni], s[mi][ni], 0, 0, 0);
    __builtin_amdgcn_s_setprio(0);

    const float mh = scale + 16.f;
    float inv_[4][4];
    #pragma unroll
    for (int mi = 0; mi < 4; ++mi) {
      #pragma unroll
      for (int r = 0; r < 4; ++r) {
        const int row = mi * 16 + crow + r;
        float es = 0.f;
        #pragma unroll
        for (int ni = 0; ni < 4; ++ni) {
          const int col = ni * 16 + fr;
          float sv = s[mi][ni][r] + btbl[h * 4096 + row * 64 + col];
          if (maskw && ((row < 32) != (col < 32))) sv -= 100.f;
          const float e = __expf(sv - mh);
          s[mi][ni][r] = e;
          es += e;
        }
        es += __shfl_xor(es, 1); es += __shfl_xor(es, 2);
        es += __shfl_xor(es, 4); es += __shfl_xor(es, 8);
        inv_[mi][r] = 1.f / fmaxf(es, 1e-37f);
      }
    }

    #pragma unroll
    for (int mi = 0; mi < 4; ++mi)
      #pragma unroll
      for (int r = 0; r < 4; ++r) {
        const int row = mi * 16 + crow + r;
        #pragma unroll
        for (int ni = 0; ni < 4; ++ni) {
          const int col = ni * 16 + fr;
          const int addr = row * 64 + (((col >> 3) ^ (row & 7)) << 3) + (col & 7);
          pl[w][addr] = f2bf(s[mi][ni][r]);
        }
      }

    f32x4 o[4][2] = {};
    #pragma unroll
    for (int ks = 0; ks < 2; ++ks) {
      bf16x8 vbf[2];
      #pragma unroll
      for (int np = 0; np < 2; ++np) {
        const int d = np * 16 + fr;
        const int jb = (lane >> 4) + ks * 4;
        vbf[np] = *(const bf16x8*)&vt[w][d * 64 + ((jb ^ (d & 7)) << 3)];
      }
      __builtin_amdgcn_s_setprio(1);
      #pragma unroll
      for (int mp = 0; mp < 4; ++mp) {
        const int row = mp * 16 + fr;
        const int cb = (lane >> 4) + ks * 4;
        bf16x8 paf = *(const bf16x8*)&pl[w][row * 64 + ((cb ^ (row & 7)) << 3)];
        o[mp][0] = __builtin_amdgcn_mfma_f32_16x16x32_bf16(paf, vbf[0], o[mp][0], 0, 0, 0);
        o[mp][1] = __builtin_amdgcn_mfma_f32_16x16x32_bf16(paf, vbf[1], o[mp][1], 0, 0, 0);
      }
      __builtin_amdgcn_s_setprio(0);
    }

    #pragma unroll
    for (int mp = 0; mp < 4; ++mp)
      #pragma unroll
      for (int r = 0; r < 4; ++r) {
        const int row = mp * 16 + crow + r;
        const float iv = inv_[mp][r];
        u16* op = attnU + ((size_t)(h >> 1) * 32768 + gg * 64 + row) * 64 + (h & 1) * 32;
        op[fr]      = f2bf(o[mp][0][r] * iv);
        op[16 + fr] = f2bf(o[mp][1][r] * iv);
      }
  }
}

// ---------------------------------------------------------------------------
// LN1 (wave-per-row): x1h = bf16( xbf + LN(roll_back(proj_out)) ), x as bf16
// ---------------------------------------------------------------------------
__global__ __launch_bounds__(256) void ln1_kernel(
    const u16* __restrict__ proj, const u16* __restrict__ xb,
    const float* __restrict__ w, const float* __restrict__ bb,
    u16* __restrict__ x1h)
{
  const int row = blockIdx.x * 4 + (threadIdx.x >> 6);
  const int lane = threadIdx.x & 63;
  const int b = row >> 12, l = row & 4095;
  const int p = (l - 32) & 4095;
  const size_t srow = (((size_t)b << 12) + p) << 9;
  const int c0 = lane * 8;
  u16x8 pv = *(const u16x8*)(proj + srow + c0);
  float v[8]; float s = 0.f, ss = 0.f;
  #pragma unroll
  for (int e = 0; e < 8; ++e) { v[e] = b2f(pv[e]); s += v[e]; ss += v[e] * v[e]; }
  #pragma unroll
  for (int o = 32; o > 0; o >>= 1) { s += __shfl_xor(s, o); ss += __shfl_xor(ss, o); }
  const float mean = s * (1.f / 512.f);
  const float var = ss * (1.f / 512.f) - mean * mean;
  const float rstd = rsqrtf(var + 1e-5f);
  const size_t orow = (size_t)row << 9;
  u16x8 xv = *(const u16x8*)(xb + orow + c0);
  u16x8 ho;
  #pragma unroll
  for (int e = 0; e < 8; ++e)
    ho[e] = f2bf(b2f(xv[e]) + (v[e] - mean) * rstd * w[c0 + e] + bb[c0 + e]);
  *(u16x8*)(x1h + orow + c0) = ho;
}

// ---------------------------------------------------------------------------
// LN2 (wave-per-row, per half): out = f32( x1 + LN(fc2_out) )
// ---------------------------------------------------------------------------
__global__ __launch_bounds__(256) void ln2_kernel(
    const u16* __restrict__ fc2, const u16* __restrict__ x1h,
    const float* __restrict__ w, const float* __restrict__ bb,
    float* __restrict__ out)
{
  const int row = blockIdx.x * 4 + (threadIdx.x >> 6);
  const int lane = threadIdx.x & 63;
  const size_t r512 = (size_t)row << 9;
  const int c0 = lane * 8;
  u16x8 pv = *(const u16x8*)(fc2 + r512 + c0);
  float v[8]; float s = 0.f, ss = 0.f;
  #pragma unroll
  for (int e = 0; e < 8; ++e) { v[e] = b2f(pv[e]); s += v[e]; ss += v[e] * v[e]; }
  #pragma unroll
  for (int o = 32; o > 0; o >>= 1) { s += __shfl_xor(s, o); ss += __shfl_xor(ss, o); }
  const float mean = s * (1.f / 512.f);
  const float var = ss * (1.f / 512.f) - mean * mean;
  const float rstd = rsqrtf(var + 1e-5f);
  u16x8 xv = *(const u16x8*)(x1h + r512 + c0);
  float r[8];
  #pragma unroll
  for (int e = 0; e < 8; ++e)
    r[e] = b2f(xv[e]) + (v[e] - mean) * rstd * w[c0 + e] + bb[c0 + e];
  float4 o0, o1;
  o0.x = r[0]; o0.y = r[1]; o0.z = r[2]; o0.w = r[3];
  o1.x = r[4]; o1.y = r[5]; o1.z = r[6]; o1.w = r[7];
  *(float4*)(out + r512 + c0) = o0;
  *(float4*)(out + r512 + c0 + 4) = o1;
}

// ---------------------------------------------------------------------------
extern "C" void kernel_launch(void* const* d_in, const int* in_sizes, int n_in,
                              void* d_out, int out_size, void* d_ws, size_t ws_size,
                              hipStream_t stream) {
  const float* x        = (const float*)d_in[0];
  const float* qkv_w    = (const float*)d_in[1];
  const float* q_bias   = (const float*)d_in[2];
  const float* v_bias   = (const float*)d_in[3];
  const float* lscale   = (const float*)d_in[4];
  const float* cpb_w1   = (const float*)d_in[5];
  const float* cpb_b1   = (const float*)d_in[6];
  const float* cpb_w2   = (const float*)d_in[7];
  const float* proj_w   = (const float*)d_in[8];
  const float* proj_b   = (const float*)d_in[9];
  const float* n1w      = (const float*)d_in[10];
  const float* n1b      = (const float*)d_in[11];
  const float* n2w      = (const float*)d_in[12];
  const float* n2b      = (const float*)d_in[13];
  const float* fc1_w    = (const float*)d_in[14];
  const float* fc1_b    = (const float*)d_in[15];
  const float* fc2_w    = (const float*)d_in[16];
  const float* fc2_b    = (const float*)d_in[17];

  if (ws_size < 134217728u) return;
  char* ws = (char*)d_ws;
  u16* wqkv   = (u16*)(ws + 0);
  u16* wproj  = (u16*)(ws + 1572864);
  u16* wfc1   = (u16*)(ws + 2097152);
  u16* wfc2   = (u16*)(ws + 4194304);
  float* btbl = (float*)(ws + 6291456);
  u16* qkv    = (u16*)(ws + 6553600);
  u16* projo  = (u16*)(ws + 6553600);    // (qkv dead after attn)
  u16* hbuf   = (u16*)(ws + 6553600);    // per half (projo dead after ln1)
  u16* fc2oh  = (u16*)(ws + 73662464);   // per half
  u16* x1h    = (u16*)(ws + 94371840);
  float* tbl  = (float*)(ws + 127926272);
  // d_out scratch: xbf [0,32MB) alive until ln1; attnU [32MB,64MB) alive
  // until proj; ln2 overwrites both with the final f32 output.
  u16* xbf   = (u16*)d_out;
  u16* attnU = (u16*)((char*)d_out + 33554432);
  float* out = (float*)d_out;

  hipFuncSetAttribute((const void*)gemm_bt<1>, hipFuncAttributeMaxDynamicSharedMemorySize, 131072);
  hipFuncSetAttribute((const void*)gemm_bt<2>, hipFuncAttributeMaxDynamicSharedMemorySize, 131072);

  cvt_all_kernel<<<19456, 256, 0, stream>>>(
      x, qkv_w, proj_w, fc1_w, fc2_w, xbf, wqkv, wproj, wfc1, wfc2);
  cpb1_kernel<<<dim3(127, 16), 64, 0, stream>>>(cpb_w1, cpb_b1, cpb_w2, tbl);
  cpb2_kernel<<<16, 256, 0, stream>>>(tbl, btbl);

  gemm_qkv<<<3072, 256, 0, stream>>>(
      xbf, wqkv, q_bias, v_bias, qkv, 12, 1536, 512);
  attn_kernel<<<512, 256, 0, stream>>>(qkv, lscale, btbl, attnU);
  gemm_bt<1><<<256, 512, 131072, stream>>>(
      attnU, wproj, proj_b, nullptr, projo, 2, 512, 512);
  ln1_kernel<<<8192, 256, 0, stream>>>(projo, xbf, n1w, n1b, x1h);
  for (int half = 0; half < 2; ++half) {
    const u16* a2 = x1h + (size_t)half * 8388608;
    gemm_bt<2><<<512, 512, 131072, stream>>>(
        a2, wfc1, fc1_b, nullptr, hbuf, 8, 2048, 512);
    gemm_sm3<<<512, 256, 0, stream>>>(
        hbuf, wfc2, fc2_b, fc2oh, 4, 512, 2048);
    ln2_kernel<<<4096, 256, 0, stream>>>(
        fc2oh, a2, n2w, n2b, out + (size_t)half * 8388608);
  }
}